// Round 12
// baseline (681.147 us; speedup 1.0000x reference)
//
#include <hip/hip_runtime.h>
#include <hip/hip_fp16.h>
#include <hip/hip_bf16.h>

// shooting_model: B=16, H=W=512, L=10, MU=0.05, KS=7, SIGMA=2
// R15: algebraic restructure -- one f32 accumulated-residual plane B and
// phi0 replace the 9-plane phi/residual history (error enters at MU^2/L).
// R16: v-blur hoisted. R17: step fused; def never touches memory.
// R18: channel-packed (f2) blurs. R19/R20/R21: register blocking.
// R22: 32x32 TILE (4 px/thread). LDS+VALU pipes balanced at 32x16; the
// remaining cost is halo redundancy. Doubling tile-y amortizes: sI
// 2.13->1.72 elem/px, sobel 1.88->1.56, h-blur 1.59->1.33, final patch
// 12->8 DS/px. ~-22% LDS issue, -15% VALU per px. LDS 23->37.2KB ->
// 4 blocks/CU (16 waves) -- fine, we're issue-bound. Same chains/clamps
// in global coords -> bit-identical numerics.

namespace {
constexpr int W_ = 512, H_ = 512, L_ = 10;
constexpr int HW_ = W_ * H_;          // 1<<18
constexpr int N_  = 16 * HW_;         // 4194304
constexpr float INVL = 0.1f;
constexpr float MU2L = 2.5e-4f;       // MU^2/L

typedef float f2 __attribute__((ext_vector_type(2)));

__device__ __constant__ f2 GW2[7] = {
    {0.07015933f, 0.07015933f}, {0.13107488f, 0.13107488f},
    {0.19071282f, 0.19071282f}, {0.21610594f, 0.21610594f},
    {0.19071282f, 0.19071282f}, {0.13107488f, 0.13107488f},
    {0.07015933f, 0.07015933f}};

struct BilL {                          // floor ints + weights
    int x0, y0;
    float w00, w01, w10, w11;
};
struct Bil {                           // + clamped float corner coords
    BilL l;
    float xc0, xc1, yc0, yc1;
};

__device__ __forceinline__ BilL mk_lite(float gx, float gy) {
    gx = fminf(fmaxf(gx, -1.0e9f), 1.0e9f);
    gy = fminf(fmaxf(gy, -1.0e9f), 1.0e9f);
    float x0f = floorf(gx), y0f = floorf(gy);
    float wx = gx - x0f, wy = gy - y0f;
    int x0 = (int)x0f, y0 = (int)y0f;
    float vx0 = ((unsigned)x0 < (unsigned)W_) ? 1.f : 0.f;
    float vx1 = ((unsigned)(x0 + 1) < (unsigned)W_) ? 1.f : 0.f;
    float vy0 = ((unsigned)y0 < (unsigned)H_) ? 1.f : 0.f;
    float vy1 = ((unsigned)(y0 + 1) < (unsigned)H_) ? 1.f : 0.f;
    BilL b;
    b.x0 = x0; b.y0 = y0;
    b.w00 = (1.f - wx) * (1.f - wy) * vx0 * vy0;
    b.w01 = wx * (1.f - wy) * vx1 * vy0;
    b.w10 = (1.f - wx) * wy * vx0 * vy1;
    b.w11 = wx * wy * vx1 * vy1;
    return b;
}

__device__ __forceinline__ Bil mk_full(float gx, float gy) {
    Bil b;
    b.l = mk_lite(gx, gy);
    int xc0 = min(max(b.l.x0, 0), W_ - 1), xc1 = min(max(b.l.x0 + 1, 0), W_ - 1);
    int yc0 = min(max(b.l.y0, 0), H_ - 1), yc1 = min(max(b.l.y0 + 1, 0), H_ - 1);
    b.xc0 = (float)xc0; b.xc1 = (float)xc1;
    b.yc0 = (float)yc0; b.yc1 = (float)yc1;
    return b;
}

__device__ __forceinline__ void gidx(const BilL& b, int& i00, int& i01,
                                     int& i10, int& i11) {
    int xc0 = min(max(b.x0, 0), W_ - 1), xc1 = min(max(b.x0 + 1, 0), W_ - 1);
    int yc0 = min(max(b.y0, 0), H_ - 1), yc1 = min(max(b.y0 + 1, 0), H_ - 1);
    i00 = yc0 * W_ + xc0; i01 = yc0 * W_ + xc1;
    i10 = yc1 * W_ + xc0; i11 = yc1 * W_ + xc1;
}

__device__ __forceinline__ float2 upk(unsigned u) {
    __half2 h; *reinterpret_cast<unsigned*>(&h) = u;
    return __half22float2(h);
}
__device__ __forceinline__ unsigned pkh(float a, float b) {
    __half2 h = __floats2half2_rn(a, b);
    return *reinterpret_cast<unsigned*>(&h);
}

// phi buffers store DISPLACEMENT (id - phi_abs) as half2, like def.
__device__ __forceinline__ void warp_from(unsigned v00, unsigned v01,
                                          unsigned v10, unsigned v11,
                                          const Bil& bw, float& wxo, float& wyo) {
    float2 s00 = upk(v00), s01 = upk(v01), s10 = upk(v10), s11 = upk(v11);
    wxo = bw.l.w00 * (bw.xc0 - s00.x) + bw.l.w01 * (bw.xc1 - s01.x)
        + bw.l.w10 * (bw.xc0 - s10.x) + bw.l.w11 * (bw.xc1 - s11.x);
    wyo = bw.l.w00 * (bw.yc0 - s00.y) + bw.l.w01 * (bw.yc0 - s01.y)
        + bw.l.w10 * (bw.yc1 - s10.y) + bw.l.w11 * (bw.yc1 - s11.y);
}

// pack src/seg f32 -> interleaved float2 (exact copy)
__global__ __launch_bounds__(256) void k_pack2(const float* __restrict__ src,
                                               const float* __restrict__ seg,
                                               float2* __restrict__ out) {
    int idx = blockIdx.x * 256 + threadIdx.x;
    out[idx] = make_float2(src[idx], seg[idx]);
}

// Fused step: dynamics (sobel -> separable blur -> v; rnext = r - div/L)
// + warp/B-update/output. def = v/L stays in LDS. 32x32 tile, 4 px/thread.
// FIRST: i==0 (phi0 == def, B = r_1). WR: write p0_new/Bnew (i<9).
template <int FIRST, int WR>
__global__ __launch_bounds__(256) void k_F(const float* __restrict__ img,
                                           const float* __restrict__ rin,
                                           float* __restrict__ rnext_f,
                                           const unsigned* __restrict__ p0_old,
                                           unsigned* __restrict__ p0_new,
                                           const float* __restrict__ Bold,
                                           float* __restrict__ Bnew,
                                           const float2* __restrict__ ss2,
                                           float* __restrict__ outp) {
    __shared__ float sI[42][43];        // img halo  (y0-5.., x0-5..), 7.2KB
    __shared__ float sR[40][41];        // r halo    (y0-4.., x0-4..), 6.6KB
    __shared__ f2 sS2[40][41];          // sobel products, 13.1KB
    __shared__ f2 sTH2[40][35];         // h-blur, 11.2KB
    // v-blur result [34][35], aliases sS2 (dead after h-blur)
    f2 (*sTV2)[35] = reinterpret_cast<f2 (*)[35]>(&sS2[0][0]);
    const int t = threadIdx.x;
    const int x0 = blockIdx.x * 32, y0 = blockIdx.y * 32, b = blockIdx.z;
    const size_t base = (size_t)b * HW_;
    const float* ip = img + base;
    const float* rp = rin + base;
    for (int u = t; u < 42 * 42; u += 256) {
        int r = u / 42, c = u % 42;
        int gy = min(max(y0 - 5 + r, 0), H_ - 1);
        int gx = min(max(x0 - 5 + c, 0), W_ - 1);
        sI[r][c] = ip[gy * W_ + gx];
    }
    for (int u = t; u < 40 * 40; u += 256) {
        int r = u / 40, c = u % 40;
        int gy = y0 - 4 + r, gx = x0 - 4 + c;
        sR[r][c] = ((unsigned)gy < (unsigned)H_ && (unsigned)gx < (unsigned)W_)
                 ? rp[gy * W_ + gx] : 0.f;
    }
    __syncthreads();
    // s = -r * sobel(img), 2x2 register block over 40x40 region (400 quads)
    for (int u = t; u < 400; u += 256) {
        int rq = u / 20, cq = u - (u / 20) * 20;
        int r = rq * 2, c = cq * 2;
        float a00 = sI[r][c],     a01 = sI[r][c + 1];
        float a02 = sI[r][c + 2], a03 = sI[r][c + 3];
        float a10 = sI[r + 1][c],     a11 = sI[r + 1][c + 1];
        float a12 = sI[r + 1][c + 2], a13 = sI[r + 1][c + 3];
        float a20 = sI[r + 2][c],     a21 = sI[r + 2][c + 1];
        float a22 = sI[r + 2][c + 2], a23 = sI[r + 2][c + 3];
        float a30 = sI[r + 3][c],     a31 = sI[r + 3][c + 1];
        float a32 = sI[r + 3][c + 2], a33 = sI[r + 3][c + 3];
        float rv00 = sR[r][c],     rv01 = sR[r][c + 1];
        float rv10 = sR[r + 1][c], rv11 = sR[r + 1][c + 1];
        float gx0 = ((a02 - a00) + 2.f * (a12 - a10) + (a22 - a20)) * 0.125f;
        float gy0 = ((a20 - a00) + 2.f * (a21 - a01) + (a22 - a02)) * 0.125f;
        float gx1 = ((a03 - a01) + 2.f * (a13 - a11) + (a23 - a21)) * 0.125f;
        float gy1 = ((a21 - a01) + 2.f * (a22 - a02) + (a23 - a03)) * 0.125f;
        float gx2 = ((a12 - a10) + 2.f * (a22 - a20) + (a32 - a30)) * 0.125f;
        float gy2 = ((a30 - a10) + 2.f * (a31 - a11) + (a32 - a12)) * 0.125f;
        float gx3 = ((a13 - a11) + 2.f * (a23 - a21) + (a33 - a31)) * 0.125f;
        float gy3 = ((a31 - a11) + 2.f * (a32 - a12) + (a33 - a13)) * 0.125f;
        f2 s0; s0.x = -rv00 * gx0; s0.y = -rv00 * gy0;
        f2 s1; s1.x = -rv01 * gx1; s1.y = -rv01 * gy1;
        f2 s2; s2.x = -rv10 * gx2; s2.y = -rv10 * gy2;
        f2 s3; s3.x = -rv11 * gx3; s3.y = -rv11 * gy3;
        sS2[r][c] = s0; sS2[r][c + 1] = s1;
        sS2[r + 1][c] = s2; sS2[r + 1][c + 1] = s3;
    }
    __syncthreads();
    // th = h-blur(s), quad-col: 40 rows x 9 quads = 360
    for (int u = t; u < 360; u += 256) {
        int r = u / 9, q = u - (u / 9) * 9;
        int c = q * 4;
        f2 w[10];
#pragma unroll
        for (int k = 0; k < 10; k++)
            w[k] = (c + k < 40) ? sS2[r][c + k] : (f2){0.f, 0.f};
#pragma unroll
        for (int j = 0; j < 4; j++) {
            if (c + j < 34) {
                f2 a = {0.f, 0.f};
#pragma unroll
                for (int k = 0; k < 7; k++)
                    a = __builtin_elementwise_fma(GW2[k], w[j + k], a);
                sTH2[r][c + j] = a;
            }
        }
    }
    __syncthreads();                           // sS2 dead; sTV2 may overwrite
    // v = v-blur(th), quad-row: 9 row-quads x 34 cols = 306
    for (int u = t; u < 306; u += 256) {
        int p = u / 34, c = u - (u / 34) * 34;
        int r = p * 4;
        f2 w[10];
#pragma unroll
        for (int k = 0; k < 10; k++)
            w[k] = (r + k < 40) ? sTH2[r + k][c] : (f2){0.f, 0.f};
#pragma unroll
        for (int j = 0; j < 4; j++) {
            if (r + j < 34) {
                f2 a = {0.f, 0.f};
#pragma unroll
                for (int k = 0; k < 7; k++)
                    a = __builtin_elementwise_fma(GW2[k], w[j + k], a);
                sTV2[r + j][c] = a;
            }
        }
    }
    __syncthreads();
    const int tx = t & 15, ty = t >> 4;        // 2x2 px/thread
    const int lx0 = tx * 2, ly0 = ty * 2;

    // shared register patches for the 2x2 px block (4 rows x 4 cols)
    float Rp[4][4]; f2 Vp[4][4];
#pragma unroll
    for (int dy = 0; dy < 4; dy++)
#pragma unroll
        for (int dx = 0; dx < 4; dx++) {
            Rp[dy][dx] = sR[ly0 + 3 + dy][lx0 + 3 + dx];
            Vp[dy][dx] = sTV2[ly0 + dy][lx0 + dx];
        }

    float rn2[4]; unsigned ph2[4];
#pragma unroll
    for (int py = 0; py < 2; py++)
#pragma unroll
    for (int px = 0; px < 2; px++) {
        const int x = x0 + lx0 + px, y = y0 + ly0 + py;
        const int pi = py * 2 + px;
        auto Vv = [&](int ch, int dy, int dx) -> float {
            f2 v = Vp[py + dy + 1][px + dx + 1];
            return ch ? v.y : v.x;
        };
        auto Wt = [&](int ch, int dy, int dx) -> float {
            int yy = y + dy, xx = x + dx;
            if ((unsigned)yy >= (unsigned)H_ || (unsigned)xx >= (unsigned)W_) return 0.f;
            return Rp[py + dy + 1][px + dx + 1] * Vv(ch, dy, dx);
        };
        float f = (Wt(0, -1, 1) - Wt(0, -1, -1)) + 2.f * (Wt(0, 0, 1) - Wt(0, 0, -1))
                + (Wt(0, 1, 1) - Wt(0, 1, -1))
                + (Wt(1, 1, -1) - Wt(1, -1, -1)) + 2.f * (Wt(1, 1, 0) - Wt(1, -1, 0))
                + (Wt(1, 1, 1) - Wt(1, -1, 1));
        f *= 0.0125f;                          // (1/8 div-kernel) * (1/L)
        rn2[pi] = Rp[py + 1][px + 1] - f;
        ph2[pi] = pkh(Vv(0, 0, 0) * INVL, Vv(1, 0, 0) * INVL);
    }

    // ---- fused step tail: warp phi0 / update B / assemble output ----
    const float2* ssp = ss2 + base;
    float Bv[4], ov[4]; unsigned p0w[4];
#pragma unroll
    for (int py = 0; py < 2; py++)
#pragma unroll
    for (int px = 0; px < 2; px++) {
        const int x = x0 + lx0 + px, y = y0 + ly0 + py;
        const int pi = py * 2 + px;
        float2 d = upk(ph2[pi]);               // same half2 round-trip
        Bil bw = mk_full((float)x - d.x, (float)y - d.y);
        float Bx = rn2[pi];
        BilL q = bw.l;
        if (!FIRST) {
            int i00, i01, i10, i11; gidx(bw.l, i00, i01, i10, i11);
            const unsigned* pp = p0_old + base;
            unsigned s00 = pp[i00], s01 = pp[i01], s10 = pp[i10], s11 = pp[i11];
            const float* Bp = Bold + base;
            float f00 = Bp[i00], f01 = Bp[i01], f10 = Bp[i10], f11 = Bp[i11];
            float wx, wy;
            warp_from(s00, s01, s10, s11, bw, wx, wy);
            Bx += f00 * bw.l.w00 + f01 * bw.l.w01 + f10 * bw.l.w10 + f11 * bw.l.w11;
            if (WR) p0w[pi] = pkh((float)x - wx, (float)y - wy);
            q = mk_lite(wx, wy);
        } else {
            if (WR) p0w[pi] = ph2[pi];         // phi0^{(0)} = def_0
        }
        int i00, i01, i10, i11; gidx(q, i00, i01, i10, i11);
        float2 c00 = ssp[i00], c01 = ssp[i01], c10 = ssp[i10], c11 = ssp[i11];
        float si = c00.x * q.w00 + c01.x * q.w01 + c10.x * q.w10 + c11.x * q.w11;
        float sg = c00.y * q.w00 + c01.y * q.w01 + c10.y * q.w10 + c11.y * q.w11;
        Bv[pi] = Bx;
        ov[pi] = si + Bx * MU2L * sg;
    }
#pragma unroll
    for (int py = 0; py < 2; py++) {
        const int idx0 = b * HW_ + (y0 + ly0 + py) * W_ + x0 + lx0;
        const int pi = py * 2;
        *reinterpret_cast<float2*>(rnext_f + idx0) = make_float2(rn2[pi], rn2[pi + 1]);
        if (WR) {
            *reinterpret_cast<uint2*>(p0_new + idx0) = make_uint2(p0w[pi], p0w[pi + 1]);
            *reinterpret_cast<float2*>(Bnew + idx0) = make_float2(Bv[pi], Bv[pi + 1]);
        }
        *reinterpret_cast<float2*>(outp + idx0) = make_float2(ov[pi], ov[pi + 1]);
    }
}

// diagnostic fallback (normalized error 0.96 signature == ws too small)
__global__ __launch_bounds__(256) void k_copy(const float* __restrict__ a,
                                              float* __restrict__ o) {
    int idx = blockIdx.x * 256 + threadIdx.x;
    o[idx] = a[idx];
}

} // namespace

extern "C" void kernel_launch(void* const* d_in, const int* in_sizes, int n_in,
                              void* d_out, int out_size, void* d_ws, size_t ws_size,
                              hipStream_t stream) {
    const float* source = (const float*)d_in[0];
    const float* z0     = (const float*)d_in[1];
    const float* seg    = (const float*)d_in[2];
    float* out = (float*)d_out;

    const size_t UNIT = (size_t)N_ * 4;          // 16 MiB
    dim3 blk(256), g1(N_ / 256), gA(16, 16, 16);

    if (ws_size < 10 * UNIT) {
        hipLaunchKernelGGL(k_copy, g1, blk, 0, stream, source, out);
        return;
    }

    char* basep = (char*)d_ws;
    float2*   ss2    = (float2*)basep;                        // u0,u1
    float*    imgA   = (float*)(basep + 2 * UNIT);            // u2 (even i)
    unsigned* phb[2] = {(unsigned*)(basep + 4 * UNIT),        // u4
                        (unsigned*)(basep + 5 * UNIT)};       // u5
    float*    Bb[2]  = {(float*)(basep + 6 * UNIT),           // u6
                        (float*)(basep + 7 * UNIT)};          // u7
    float*    rnb[2] = {(float*)(basep + 8 * UNIT),           // u8
                        (float*)(basep + 9 * UNIT)};          // u9

    hipLaunchKernelGGL(k_pack2, g1, blk, 0, stream, source, seg, ss2);

    // F0: img=source, rin=z0 -> writes rnb[0], phb[0], Bb[0], imgA
    hipLaunchKernelGGL((k_F<1, 1>), gA, blk, 0, stream,
                       source, z0, rnb[0], (const unsigned*)nullptr, phb[0],
                       (const float*)nullptr, Bb[0], (const float2*)ss2, imgA);

    // F1..F9: odd i -> writes d_out; even i -> writes imgA. F9 -> d_out.
    for (int i = 1; i < L_; i++) {
        const float* img = (i & 1) ? imgA : out;   // written by F_{i-1}
        float* outp      = (i & 1) ? out : imgA;
        const float* rin = rnb[(i - 1) & 1];
        float* rn_w      = rnb[i & 1];
        const unsigned* p0o = phb[(i - 1) & 1];
        unsigned* p0n       = phb[i & 1];
        const float* Bo  = Bb[(i - 1) & 1];
        float* Bn        = Bb[i & 1];
        if (i < L_ - 1)
            hipLaunchKernelGGL((k_F<0, 1>), gA, blk, 0, stream,
                               img, rin, rn_w, p0o, p0n, Bo, Bn,
                               (const float2*)ss2, outp);
        else
            hipLaunchKernelGGL((k_F<0, 0>), gA, blk, 0, stream,
                               img, rin, rn_w, p0o, p0n, Bo, Bn,
                               (const float2*)ss2, outp);
    }
    (void)in_sizes; (void)n_in; (void)out_size;
}

// Round 13
// 597.743 us; speedup vs baseline: 1.1395x; 1.1395x over previous
//
#include <hip/hip_runtime.h>
#include <hip/hip_fp16.h>
#include <hip/hip_bf16.h>

// shooting_model: B=16, H=W=512, L=10, MU=0.05, KS=7, SIGMA=2
// R15: algebraic restructure -- one f32 accumulated-residual plane B and
// phi0 replace the 9-plane phi/residual history (error enters at MU^2/L).
// R16: v-blur hoisted. R17: step fused; def never touches memory.
// R18: channel-packed (f2) blurs. R19/R20/R21: register blocking.
// R22: 32x32 tile halved per-px halo work but LDS 38.4KB at 256 thr
// -> 16 waves/CU (occ 37%), latency-starved: REGRESSED 59.6->65 us.
// R23: same 32x32 tile + 512-THREAD blocks: 4 blocks/CU x 8 waves = 32
// waves/CU (R21's wave count) with R22's per-px savings. Passes are
// single-shot (sobel 400 quads, h 360, v 306 < 512). Final: 2 px/thread
// (R20 3x4 patch). Identical chains -> bit-identical numerics.

namespace {
constexpr int W_ = 512, H_ = 512, L_ = 10;
constexpr int HW_ = W_ * H_;          // 1<<18
constexpr int N_  = 16 * HW_;         // 4194304
constexpr float INVL = 0.1f;
constexpr float MU2L = 2.5e-4f;       // MU^2/L

typedef float f2 __attribute__((ext_vector_type(2)));

__device__ __constant__ f2 GW2[7] = {
    {0.07015933f, 0.07015933f}, {0.13107488f, 0.13107488f},
    {0.19071282f, 0.19071282f}, {0.21610594f, 0.21610594f},
    {0.19071282f, 0.19071282f}, {0.13107488f, 0.13107488f},
    {0.07015933f, 0.07015933f}};

struct BilL {                          // floor ints + weights
    int x0, y0;
    float w00, w01, w10, w11;
};
struct Bil {                           // + clamped float corner coords
    BilL l;
    float xc0, xc1, yc0, yc1;
};

__device__ __forceinline__ BilL mk_lite(float gx, float gy) {
    gx = fminf(fmaxf(gx, -1.0e9f), 1.0e9f);
    gy = fminf(fmaxf(gy, -1.0e9f), 1.0e9f);
    float x0f = floorf(gx), y0f = floorf(gy);
    float wx = gx - x0f, wy = gy - y0f;
    int x0 = (int)x0f, y0 = (int)y0f;
    float vx0 = ((unsigned)x0 < (unsigned)W_) ? 1.f : 0.f;
    float vx1 = ((unsigned)(x0 + 1) < (unsigned)W_) ? 1.f : 0.f;
    float vy0 = ((unsigned)y0 < (unsigned)H_) ? 1.f : 0.f;
    float vy1 = ((unsigned)(y0 + 1) < (unsigned)H_) ? 1.f : 0.f;
    BilL b;
    b.x0 = x0; b.y0 = y0;
    b.w00 = (1.f - wx) * (1.f - wy) * vx0 * vy0;
    b.w01 = wx * (1.f - wy) * vx1 * vy0;
    b.w10 = (1.f - wx) * wy * vx0 * vy1;
    b.w11 = wx * wy * vx1 * vy1;
    return b;
}

__device__ __forceinline__ Bil mk_full(float gx, float gy) {
    Bil b;
    b.l = mk_lite(gx, gy);
    int xc0 = min(max(b.l.x0, 0), W_ - 1), xc1 = min(max(b.l.x0 + 1, 0), W_ - 1);
    int yc0 = min(max(b.l.y0, 0), H_ - 1), yc1 = min(max(b.l.y0 + 1, 0), H_ - 1);
    b.xc0 = (float)xc0; b.xc1 = (float)xc1;
    b.yc0 = (float)yc0; b.yc1 = (float)yc1;
    return b;
}

__device__ __forceinline__ void gidx(const BilL& b, int& i00, int& i01,
                                     int& i10, int& i11) {
    int xc0 = min(max(b.x0, 0), W_ - 1), xc1 = min(max(b.x0 + 1, 0), W_ - 1);
    int yc0 = min(max(b.y0, 0), H_ - 1), yc1 = min(max(b.y0 + 1, 0), H_ - 1);
    i00 = yc0 * W_ + xc0; i01 = yc0 * W_ + xc1;
    i10 = yc1 * W_ + xc0; i11 = yc1 * W_ + xc1;
}

__device__ __forceinline__ float2 upk(unsigned u) {
    __half2 h; *reinterpret_cast<unsigned*>(&h) = u;
    return __half22float2(h);
}
__device__ __forceinline__ unsigned pkh(float a, float b) {
    __half2 h = __floats2half2_rn(a, b);
    return *reinterpret_cast<unsigned*>(&h);
}

// phi buffers store DISPLACEMENT (id - phi_abs) as half2, like def.
__device__ __forceinline__ void warp_from(unsigned v00, unsigned v01,
                                          unsigned v10, unsigned v11,
                                          const Bil& bw, float& wxo, float& wyo) {
    float2 s00 = upk(v00), s01 = upk(v01), s10 = upk(v10), s11 = upk(v11);
    wxo = bw.l.w00 * (bw.xc0 - s00.x) + bw.l.w01 * (bw.xc1 - s01.x)
        + bw.l.w10 * (bw.xc0 - s10.x) + bw.l.w11 * (bw.xc1 - s11.x);
    wyo = bw.l.w00 * (bw.yc0 - s00.y) + bw.l.w01 * (bw.yc0 - s01.y)
        + bw.l.w10 * (bw.yc1 - s10.y) + bw.l.w11 * (bw.yc1 - s11.y);
}

// pack src/seg f32 -> interleaved float2 (exact copy)
__global__ __launch_bounds__(256) void k_pack2(const float* __restrict__ src,
                                               const float* __restrict__ seg,
                                               float2* __restrict__ out) {
    int idx = blockIdx.x * 256 + threadIdx.x;
    out[idx] = make_float2(src[idx], seg[idx]);
}

// Fused step: dynamics (sobel -> separable blur -> v; rnext = r - div/L)
// + warp/B-update/output. 32x32 tile, 512 threads, 2 px/thread.
// FIRST: i==0 (phi0 == def, B = r_1). WR: write p0_new/Bnew (i<9).
template <int FIRST, int WR>
__global__ __launch_bounds__(512) void k_F(const float* __restrict__ img,
                                           const float* __restrict__ rin,
                                           float* __restrict__ rnext_f,
                                           const unsigned* __restrict__ p0_old,
                                           unsigned* __restrict__ p0_new,
                                           const float* __restrict__ Bold,
                                           float* __restrict__ Bnew,
                                           const float2* __restrict__ ss2,
                                           float* __restrict__ outp) {
    __shared__ float sI[42][43];        // img halo  (y0-5.., x0-5..), 7.2KB
    __shared__ float sR[40][41];        // r halo    (y0-4.., x0-4..), 6.6KB
    __shared__ f2 sS2[40][41];          // sobel products, 13.1KB
    __shared__ f2 sTH2[40][35];         // h-blur, 11.2KB
    // v-blur result [34][35], aliases sS2 (dead after h-blur)
    f2 (*sTV2)[35] = reinterpret_cast<f2 (*)[35]>(&sS2[0][0]);
    const int t = threadIdx.x;
    const int x0 = blockIdx.x * 32, y0 = blockIdx.y * 32, b = blockIdx.z;
    const size_t base = (size_t)b * HW_;
    const float* ip = img + base;
    const float* rp = rin + base;
    for (int u = t; u < 42 * 42; u += 512) {
        int r = u / 42, c = u % 42;
        int gy = min(max(y0 - 5 + r, 0), H_ - 1);
        int gx = min(max(x0 - 5 + c, 0), W_ - 1);
        sI[r][c] = ip[gy * W_ + gx];
    }
    for (int u = t; u < 40 * 40; u += 512) {
        int r = u / 40, c = u % 40;
        int gy = y0 - 4 + r, gx = x0 - 4 + c;
        sR[r][c] = ((unsigned)gy < (unsigned)H_ && (unsigned)gx < (unsigned)W_)
                 ? rp[gy * W_ + gx] : 0.f;
    }
    __syncthreads();
    // s = -r * sobel(img), 2x2 register block over 40x40 region (400 quads)
    if (t < 400) {
        int rq = t / 20, cq = t - (t / 20) * 20;
        int r = rq * 2, c = cq * 2;
        float a00 = sI[r][c],     a01 = sI[r][c + 1];
        float a02 = sI[r][c + 2], a03 = sI[r][c + 3];
        float a10 = sI[r + 1][c],     a11 = sI[r + 1][c + 1];
        float a12 = sI[r + 1][c + 2], a13 = sI[r + 1][c + 3];
        float a20 = sI[r + 2][c],     a21 = sI[r + 2][c + 1];
        float a22 = sI[r + 2][c + 2], a23 = sI[r + 2][c + 3];
        float a30 = sI[r + 3][c],     a31 = sI[r + 3][c + 1];
        float a32 = sI[r + 3][c + 2], a33 = sI[r + 3][c + 3];
        float rv00 = sR[r][c],     rv01 = sR[r][c + 1];
        float rv10 = sR[r + 1][c], rv11 = sR[r + 1][c + 1];
        float gx0 = ((a02 - a00) + 2.f * (a12 - a10) + (a22 - a20)) * 0.125f;
        float gy0 = ((a20 - a00) + 2.f * (a21 - a01) + (a22 - a02)) * 0.125f;
        float gx1 = ((a03 - a01) + 2.f * (a13 - a11) + (a23 - a21)) * 0.125f;
        float gy1 = ((a21 - a01) + 2.f * (a22 - a02) + (a23 - a03)) * 0.125f;
        float gx2 = ((a12 - a10) + 2.f * (a22 - a20) + (a32 - a30)) * 0.125f;
        float gy2 = ((a30 - a10) + 2.f * (a31 - a11) + (a32 - a12)) * 0.125f;
        float gx3 = ((a13 - a11) + 2.f * (a23 - a21) + (a33 - a31)) * 0.125f;
        float gy3 = ((a31 - a11) + 2.f * (a32 - a12) + (a33 - a13)) * 0.125f;
        f2 s0; s0.x = -rv00 * gx0; s0.y = -rv00 * gy0;
        f2 s1; s1.x = -rv01 * gx1; s1.y = -rv01 * gy1;
        f2 s2; s2.x = -rv10 * gx2; s2.y = -rv10 * gy2;
        f2 s3; s3.x = -rv11 * gx3; s3.y = -rv11 * gy3;
        sS2[r][c] = s0; sS2[r][c + 1] = s1;
        sS2[r + 1][c] = s2; sS2[r + 1][c + 1] = s3;
    }
    __syncthreads();
    // th = h-blur(s), quad-col: 40 rows x 9 quads = 360
    if (t < 360) {
        int r = t / 9, q = t - (t / 9) * 9;
        int c = q * 4;
        f2 w[10];
#pragma unroll
        for (int k = 0; k < 10; k++)
            w[k] = (c + k < 40) ? sS2[r][c + k] : (f2){0.f, 0.f};
#pragma unroll
        for (int j = 0; j < 4; j++) {
            if (c + j < 34) {
                f2 a = {0.f, 0.f};
#pragma unroll
                for (int k = 0; k < 7; k++)
                    a = __builtin_elementwise_fma(GW2[k], w[j + k], a);
                sTH2[r][c + j] = a;
            }
        }
    }
    __syncthreads();                           // sS2 dead; sTV2 may overwrite
    // v = v-blur(th), quad-row: 9 row-quads x 34 cols = 306
    if (t < 306) {
        int p = t / 34, c = t - (t / 34) * 34;
        int r = p * 4;
        f2 w[10];
#pragma unroll
        for (int k = 0; k < 10; k++)
            w[k] = (r + k < 40) ? sTH2[r + k][c] : (f2){0.f, 0.f};
#pragma unroll
        for (int j = 0; j < 4; j++) {
            if (r + j < 34) {
                f2 a = {0.f, 0.f};
#pragma unroll
                for (int k = 0; k < 7; k++)
                    a = __builtin_elementwise_fma(GW2[k], w[j + k], a);
                sTV2[r + j][c] = a;
            }
        }
    }
    __syncthreads();
    const int tx = t & 15, ty = t >> 4;        // 2 px/thread in x; ty in [0,32)
    const int lx0 = tx * 2;
    const int y = y0 + ty;

    // shared register patches for the px pair (3 rows x 4 cols)
    float Rp[3][4]; f2 Vp[3][4];
#pragma unroll
    for (int dy = 0; dy < 3; dy++)
#pragma unroll
        for (int dx = 0; dx < 4; dx++) {
            Rp[dy][dx] = sR[ty + 3 + dy][lx0 + 3 + dx];
            Vp[dy][dx] = sTV2[ty + dy][lx0 + dx];
        }

    float rn2[2]; unsigned ph2[2];
#pragma unroll
    for (int px = 0; px < 2; px++) {
        const int x = x0 + lx0 + px;
        auto Vv = [&](int ch, int dy, int dx) -> float {
            f2 v = Vp[dy + 1][px + dx + 1];
            return ch ? v.y : v.x;
        };
        auto Wt = [&](int ch, int dy, int dx) -> float {
            int yy = y + dy, xx = x + dx;
            if ((unsigned)yy >= (unsigned)H_ || (unsigned)xx >= (unsigned)W_) return 0.f;
            return Rp[dy + 1][px + dx + 1] * Vv(ch, dy, dx);
        };
        float f = (Wt(0, -1, 1) - Wt(0, -1, -1)) + 2.f * (Wt(0, 0, 1) - Wt(0, 0, -1))
                + (Wt(0, 1, 1) - Wt(0, 1, -1))
                + (Wt(1, 1, -1) - Wt(1, -1, -1)) + 2.f * (Wt(1, 1, 0) - Wt(1, -1, 0))
                + (Wt(1, 1, 1) - Wt(1, -1, 1));
        f *= 0.0125f;                          // (1/8 div-kernel) * (1/L)
        rn2[px] = Rp[1][px + 1] - f;
        ph2[px] = pkh(Vv(0, 0, 0) * INVL, Vv(1, 0, 0) * INVL);
    }
    const int idx0 = b * HW_ + y * W_ + x0 + lx0; // even
    *reinterpret_cast<float2*>(rnext_f + idx0) = make_float2(rn2[0], rn2[1]);

    // ---- fused step tail: warp phi0 / update B / assemble output ----
    const float2* ssp = ss2 + base;
    float Bv[2], ov[2]; unsigned p0w[2];
#pragma unroll
    for (int px = 0; px < 2; px++) {
        const int x = x0 + lx0 + px;
        float2 d = upk(ph2[px]);               // same half2 round-trip
        Bil bw = mk_full((float)x - d.x, (float)y - d.y);
        float Bx = rn2[px];
        BilL q = bw.l;
        if (!FIRST) {
            int i00, i01, i10, i11; gidx(bw.l, i00, i01, i10, i11);
            const unsigned* pp = p0_old + base;
            unsigned s00 = pp[i00], s01 = pp[i01], s10 = pp[i10], s11 = pp[i11];
            const float* Bp = Bold + base;
            float f00 = Bp[i00], f01 = Bp[i01], f10 = Bp[i10], f11 = Bp[i11];
            float wx, wy;
            warp_from(s00, s01, s10, s11, bw, wx, wy);
            Bx += f00 * bw.l.w00 + f01 * bw.l.w01 + f10 * bw.l.w10 + f11 * bw.l.w11;
            if (WR) p0w[px] = pkh((float)x - wx, (float)y - wy);
            q = mk_lite(wx, wy);
        } else {
            if (WR) p0w[px] = ph2[px];         // phi0^{(0)} = def_0
        }
        int i00, i01, i10, i11; gidx(q, i00, i01, i10, i11);
        float2 c00 = ssp[i00], c01 = ssp[i01], c10 = ssp[i10], c11 = ssp[i11];
        float si = c00.x * q.w00 + c01.x * q.w01 + c10.x * q.w10 + c11.x * q.w11;
        float sg = c00.y * q.w00 + c01.y * q.w01 + c10.y * q.w10 + c11.y * q.w11;
        Bv[px] = Bx;
        ov[px] = si + Bx * MU2L * sg;
    }
    if (WR) {
        *reinterpret_cast<uint2*>(p0_new + idx0) = make_uint2(p0w[0], p0w[1]);
        *reinterpret_cast<float2*>(Bnew + idx0) = make_float2(Bv[0], Bv[1]);
    }
    *reinterpret_cast<float2*>(outp + idx0) = make_float2(ov[0], ov[1]);
}

// diagnostic fallback (normalized error 0.96 signature == ws too small)
__global__ __launch_bounds__(256) void k_copy(const float* __restrict__ a,
                                              float* __restrict__ o) {
    int idx = blockIdx.x * 256 + threadIdx.x;
    o[idx] = a[idx];
}

} // namespace

extern "C" void kernel_launch(void* const* d_in, const int* in_sizes, int n_in,
                              void* d_out, int out_size, void* d_ws, size_t ws_size,
                              hipStream_t stream) {
    const float* source = (const float*)d_in[0];
    const float* z0     = (const float*)d_in[1];
    const float* seg    = (const float*)d_in[2];
    float* out = (float*)d_out;

    const size_t UNIT = (size_t)N_ * 4;          // 16 MiB
    dim3 blk(256), blkF(512), g1(N_ / 256), gA(16, 16, 16);

    if (ws_size < 10 * UNIT) {
        hipLaunchKernelGGL(k_copy, g1, blk, 0, stream, source, out);
        return;
    }

    char* basep = (char*)d_ws;
    float2*   ss2    = (float2*)basep;                        // u0,u1
    float*    imgA   = (float*)(basep + 2 * UNIT);            // u2 (even i)
    unsigned* phb[2] = {(unsigned*)(basep + 4 * UNIT),        // u4
                        (unsigned*)(basep + 5 * UNIT)};       // u5
    float*    Bb[2]  = {(float*)(basep + 6 * UNIT),           // u6
                        (float*)(basep + 7 * UNIT)};          // u7
    float*    rnb[2] = {(float*)(basep + 8 * UNIT),           // u8
                        (float*)(basep + 9 * UNIT)};          // u9

    hipLaunchKernelGGL(k_pack2, g1, blk, 0, stream, source, seg, ss2);

    // F0: img=source, rin=z0 -> writes rnb[0], phb[0], Bb[0], imgA
    hipLaunchKernelGGL((k_F<1, 1>), gA, blkF, 0, stream,
                       source, z0, rnb[0], (const unsigned*)nullptr, phb[0],
                       (const float*)nullptr, Bb[0], (const float2*)ss2, imgA);

    // F1..F9: odd i -> writes d_out; even i -> writes imgA. F9 -> d_out.
    for (int i = 1; i < L_; i++) {
        const float* img = (i & 1) ? imgA : out;   // written by F_{i-1}
        float* outp      = (i & 1) ? out : imgA;
        const float* rin = rnb[(i - 1) & 1];
        float* rn_w      = rnb[i & 1];
        const unsigned* p0o = phb[(i - 1) & 1];
        unsigned* p0n       = phb[i & 1];
        const float* Bo  = Bb[(i - 1) & 1];
        float* Bn        = Bb[i & 1];
        if (i < L_ - 1)
            hipLaunchKernelGGL((k_F<0, 1>), gA, blkF, 0, stream,
                               img, rin, rn_w, p0o, p0n, Bo, Bn,
                               (const float2*)ss2, outp);
        else
            hipLaunchKernelGGL((k_F<0, 0>), gA, blkF, 0, stream,
                               img, rin, rn_w, p0o, p0n, Bo, Bn,
                               (const float2*)ss2, outp);
    }
    (void)in_sizes; (void)n_in; (void)out_size;
}